// Round 9
// baseline (261.464 us; speedup 1.0000x reference)
//
#include <hip/hip_runtime.h>

#define N_NODES 50000
#define N_EDGES 600000
#define HDIM 128
#define NGRAPH 500
#define NCLASS 10
#define BN_EPS 1e-5f
#define KSLOT 64
#define KSTRIDE 72   // 64 slots + 8 pad so next-batch int4 prefetch is always in-bounds

typedef short short8 __attribute__((ext_vector_type(8)));
typedef float floatx4 __attribute__((ext_vector_type(4)));

__device__ __forceinline__ float bf2f(unsigned short u) {
    unsigned int v = ((unsigned int)u) << 16;
    return __uint_as_float(v);
}
__device__ __forceinline__ unsigned short f2bf(float f) {
    unsigned int u = __float_as_uint(f);
    unsigned int r = (u + 0x7fffu + ((u >> 16) & 1u)) >> 16;
    return (unsigned short)r;
}

// ---------------- fused setup: castx | zero cnt | prepW | prep(ep) ----------------
#define NB_CAST 6250
#define NB_ZERO 196
#define NB_PREPW 256
#define NB_SETUP (NB_CAST + NB_ZERO + NB_PREPW + 1)

// W packs (4 x 16384 bf16), frag index: (((ct*4+s)*4+q)*16+m)*8+j
//  w=0 (W1a) / w=2 (W2a): A-operand pack, k = s*32+q*8+j,            val = W[k][n]
//  w=1 (W1b) / w=3 (W2b): B-operand pack, k = pi(s,q,j),             val = W[k][n] (*s2[k] for w=3)
// pi(s,q,j) = (s*2+(j>>2))*16 + q*4 + (j&3)
__global__ void k_setup(const float* __restrict__ x, unsigned short* __restrict__ xb,
                        int* __restrict__ cnt,
                        const float* __restrict__ W1a, const float* __restrict__ W1b,
                        const float* __restrict__ W2a, const float* __restrict__ W2b,
                        unsigned short* __restrict__ wpack,
                        const float* __restrict__ b1a, const float* __restrict__ g1,
                        const float* __restrict__ be1, const float* __restrict__ m1,
                        const float* __restrict__ v1, const float* __restrict__ b1b,
                        const float* __restrict__ b2a, const float* __restrict__ g2,
                        const float* __restrict__ be2, const float* __restrict__ m2,
                        const float* __restrict__ v2, const float* __restrict__ b2b,
                        float* __restrict__ ep) {
    int b = blockIdx.x;
    int t = threadIdx.x;
    if (b < NB_CAST) {
        int i = b * 256 + t;   // over 1.6M float4
        float4 v = ((const float4*)x)[i];
        ushort4 o;
        o.x = f2bf(v.x); o.y = f2bf(v.y); o.z = f2bf(v.z); o.w = f2bf(v.w);
        ((ushort4*)xb)[i] = o;
        return;
    }
    b -= NB_CAST;
    if (b < NB_ZERO) {
        int i = b * 256 + t;
        if (i < N_NODES) cnt[i] = 0;
        return;
    }
    b -= NB_ZERO;
    if (b < NB_PREPW) {
        int e = b * 256 + t;               // 0..65535
        int w = e >> 14;
        int s_ = e & 16383;
        int j = s_ & 7;
        int m = (s_ >> 3) & 15;
        int q = (s_ >> 7) & 3;
        int ks = (s_ >> 9) & 3;
        int ct = (s_ >> 11) & 7;
        int n = ct * 16 + m;
        int k;
        float scale = 1.f;
        if (w == 0 || w == 2) {
            k = ks * 32 + q * 8 + j;
        } else {
            k = (ks * 2 + (j >> 2)) * 16 + q * 4 + (j & 3);
            if (w == 3) scale = g2[k] * rsqrtf(v2[k] + BN_EPS);
        }
        const float* W = (w == 0) ? W1a : (w == 1) ? W1b : (w == 2) ? W2a : W2b;
        wpack[e] = f2bf(W[k * 128 + n] * scale);
        return;
    }
    // ep layout: epi[conv][{P,Q}][128] at conv*256, epf[conv][128] at 512+conv*128
    if (t < 128) {
        int j = t;
        float s1 = g1[j] * rsqrtf(v1[j] + BN_EPS);
        ep[0 * 256 + 0 + j]   = s1;
        ep[0 * 256 + 128 + j] = (b1a[j] - m1[j]) * s1 + be1[j];
        ep[1 * 256 + 0 + j]   = 1.f;
        ep[1 * 256 + 128 + j] = b2a[j];
        ep[512 + j] = b1b[j];
        float acc = b2b[j];
        for (int k = 0; k < 128; k++) {
            float s2k = g2[k] * rsqrtf(v2[k] + BN_EPS);
            acc += (be2[k] - m2[k] * s2k) * W2b[k * 128 + j];
        }
        ep[512 + 128 + j] = acc;
    }
}

// ---------------- slot-CSR scatter: adj[dst*KSTRIDE+pos] = src ----------------
__global__ void k_scatter(const int* __restrict__ src, const int* __restrict__ dst,
                          int* __restrict__ cnt, int* __restrict__ adj, int e) {
    int i = blockIdx.x * blockDim.x + threadIdx.x;
    if (i < e) {
        int d = dst[i];
        int p = atomicAdd(&cnt[d], 1);
        if (p < KSLOT) adj[d * KSTRIDE + p] = src[i];
    }
}

// ---------------- aggregation: out[i] = x[i] + sum_{j->i} x[j] ----------------
// 16 lanes/node, 4 nodes/wave, 3125 blocks. Software-pipelined 8-edge batches:
// next batch's int4 index loads issue while current batch's row gathers are in
// flight (pad-stride bins make the prefetch always in-bounds). Slots >= len are
// clamped to `node` (self row, L1-hot); the over-count is removed once at the end.
__global__ __launch_bounds__(256) void k_agg(const unsigned short* __restrict__ x,
                                             const int* __restrict__ cnt,
                                             const int* __restrict__ adj,
                                             unsigned short* __restrict__ out) {
    int g = blockIdx.x * 256 + threadIdx.x;
    int node = g >> 4;
    int m = g & 15;
    if (node >= N_NODES) return;

    int len = cnt[node];
    if (len > KSLOT) len = KSLOT;
    const int* ad = adj + node * KSTRIDE;

    // first batch's indices (in-bounds: bin has 72 slots)
    int4 ra = *(const int4*)(ad);
    int4 rb = *(const int4*)(ad + 4);

    float self[8];
    {
        short8 sv = *(const short8*)(x + (size_t)node * 128 + m * 8);
        #pragma unroll
        for (int j = 0; j < 8; j++) self[j] = bf2f((unsigned short)sv[j]);
    }
    float acc[8];
    #pragma unroll
    for (int j = 0; j < 8; j++) acc[j] = self[j];

    int nb = (len + 7) >> 3;     // full batches, clamped slots
    for (int b = 0; b < nb; b++) {
        int i = b * 8;
        // prefetch next batch's indices (pad keeps this in-bounds)
        int4 na = *(const int4*)(ad + i + 8);
        int4 nbv = *(const int4*)(ad + i + 12);
        // clamp current indices: slot >= len -> self (L1-hot line)
        int u0 = (i + 0 < len) ? ra.x : node;
        int u1 = (i + 1 < len) ? ra.y : node;
        int u2 = (i + 2 < len) ? ra.z : node;
        int u3 = (i + 3 < len) ? ra.w : node;
        int u4 = (i + 4 < len) ? rb.x : node;
        int u5 = (i + 5 < len) ? rb.y : node;
        int u6 = (i + 6 < len) ? rb.z : node;
        int u7 = (i + 7 < len) ? rb.w : node;
        short8 f0 = *(const short8*)(x + (size_t)u0 * 128 + m * 8);
        short8 f1 = *(const short8*)(x + (size_t)u1 * 128 + m * 8);
        short8 f2 = *(const short8*)(x + (size_t)u2 * 128 + m * 8);
        short8 f3 = *(const short8*)(x + (size_t)u3 * 128 + m * 8);
        short8 f4 = *(const short8*)(x + (size_t)u4 * 128 + m * 8);
        short8 f5 = *(const short8*)(x + (size_t)u5 * 128 + m * 8);
        short8 f6 = *(const short8*)(x + (size_t)u6 * 128 + m * 8);
        short8 f7 = *(const short8*)(x + (size_t)u7 * 128 + m * 8);
        #pragma unroll
        for (int j = 0; j < 8; j++) {
            float a = bf2f((unsigned short)f0[j]) + bf2f((unsigned short)f1[j]) +
                      bf2f((unsigned short)f2[j]) + bf2f((unsigned short)f3[j]);
            float c = bf2f((unsigned short)f4[j]) + bf2f((unsigned short)f5[j]) +
                      bf2f((unsigned short)f6[j]) + bf2f((unsigned short)f7[j]);
            acc[j] += a + c;
        }
        ra = na; rb = nbv;
    }
    // remove the clamped-slot over-count: (nb*8 - len) copies of self
    float extra = (float)(nb * 8 - len);
    #pragma unroll
    for (int j = 0; j < 8; j++) acc[j] -= extra * self[j];

    short8 r;
    #pragma unroll
    for (int j = 0; j < 8; j++) r[j] = (short)f2bf(acc[j]);
    *(short8*)(out + (size_t)node * 128 + m * 8) = r;
}

// ---------------- fused MLP: Out = relu(relu(A@Wa *P+Q) @ Wb + Qf) ----------------
// 64 rows/block (1 row-tile/wave), 782 blocks, NO LDS (W frags L1/L2-hot).
// gemm1 operand-swapped -> C1^T (node=lane&15, feat=q*4+reg); pi-permuted Wb pack
// feeds gemm2 A-frags directly in-register.
__global__ __launch_bounds__(256, 4) void k_mlp(const unsigned short* __restrict__ A,
                                                const unsigned short* __restrict__ WaP,
                                                const unsigned short* __restrict__ WbP,
                                                const float* __restrict__ epi,   // P[128],Q[128]
                                                const float* __restrict__ epf,   // Qf[128]
                                                unsigned short* __restrict__ Out, int n) {
    int t = threadIdx.x;
    int lane = t & 63;
    int w = t >> 6;
    int q = lane >> 4;
    int m = lane & 15;

    int base = blockIdx.x * 64 + w * 16;
    int node = base + m;
    if (node >= n) node = n - 1;

    short8 a1[4];
    #pragma unroll
    for (int s = 0; s < 4; s++)
        a1[s] = *(const short8*)(A + (size_t)node * 128 + s * 32 + q * 8);

    int lbase = lane * 8;

    // gemm1 (swapped): acc1[ct] over feature tiles
    floatx4 acc1[8];
    #pragma unroll
    for (int c = 0; c < 8; c++) acc1[c] = (floatx4)0.f;
    #pragma unroll
    for (int s = 0; s < 4; s++) {
        #pragma unroll
        for (int ct = 0; ct < 8; ct++) {
            short8 wf = *(const short8*)(WaP + (ct * 4 + s) * 512 + lbase);
            acc1[ct] = __builtin_amdgcn_mfma_f32_16x16x32_bf16(wf, a1[s], acc1[ct], 0, 0, 0);
        }
    }

    // inter-epilogue + repack into gemm2 A-frags (pure per-lane)
    short8 a2[4];
    #pragma unroll
    for (int s = 0; s < 4; s++) {
        #pragma unroll
        for (int j = 0; j < 8; j++) {
            int ct = s * 2 + (j >> 2);
            int r = j & 3;
            int col = ct * 16 + q * 4 + r;
            float P = epi[col], Q = epi[128 + col];
            float v = fmaxf(fmaf(acc1[ct][r], P, Q), 0.f);
            a2[s][j] = (short)f2bf(v);
        }
    }

    // gemm2 (standard): D rows = nodes (q*4+r), cols = features (lane&15)
    floatx4 acc2[8];
    #pragma unroll
    for (int c = 0; c < 8; c++) acc2[c] = (floatx4)0.f;
    #pragma unroll
    for (int s = 0; s < 4; s++) {
        #pragma unroll
        for (int ct = 0; ct < 8; ct++) {
            short8 wf = *(const short8*)(WbP + (ct * 4 + s) * 512 + lbase);
            acc2[ct] = __builtin_amdgcn_mfma_f32_16x16x32_bf16(a2[s], wf, acc2[ct], 0, 0, 0);
        }
    }

    // final epilogue: relu(y + Qf), 2B stores (quad-contiguous 32B segments)
    #pragma unroll
    for (int ct = 0; ct < 8; ct++) {
        int col = ct * 16 + m;
        float Qf = epf[col];
        #pragma unroll
        for (int r = 0; r < 4; r++) {
            int gr = base + q * 4 + r;
            if (gr < n)
                Out[(size_t)gr * 128 + col] = f2bf(fmaxf(acc2[ct][r] + Qf, 0.f));
        }
    }
}

// ---------------- pooling + head, one block (256 thr = 4 waves) per graph ----------------
__global__ void k_pool_head(const unsigned short* __restrict__ h1, const unsigned short* __restrict__ h2,
                            const int* __restrict__ batch, const float* __restrict__ Wl1,
                            const float* __restrict__ bl1, const float* __restrict__ Wl2,
                            const float* __restrict__ bl2, float* __restrict__ out) {
    int g = blockIdx.x;
    int t = threadIdx.x;
    int lo = 0, hi = N_NODES;
    while (lo < hi) { int mid = (lo + hi) >> 1; if (batch[mid] < g) lo = mid + 1; else hi = mid; }
    int start = lo;
    lo = 0; hi = N_NODES;
    while (lo < hi) { int mid = (lo + hi) >> 1; if (batch[mid] < g + 1) lo = mid + 1; else hi = mid; }
    int end = lo;

    int w = t >> 6, l = t & 63;
    const unsigned int* h = (w < 2) ? (const unsigned int*)h1 : (const unsigned int*)h2;
    int sub = w & 1;
    float ax = 0.f, ay = 0.f;
    int i = start + sub;
    for (; i + 6 < end; i += 8) {
        unsigned int v0 = h[(size_t)(i + 0) * 64 + l];
        unsigned int v1 = h[(size_t)(i + 2) * 64 + l];
        unsigned int v2 = h[(size_t)(i + 4) * 64 + l];
        unsigned int v3 = h[(size_t)(i + 6) * 64 + l];
        ax += bf2f((unsigned short)(v0 & 0xffff)) + bf2f((unsigned short)(v1 & 0xffff)) +
              bf2f((unsigned short)(v2 & 0xffff)) + bf2f((unsigned short)(v3 & 0xffff));
        ay += bf2f((unsigned short)(v0 >> 16)) + bf2f((unsigned short)(v1 >> 16)) +
              bf2f((unsigned short)(v2 >> 16)) + bf2f((unsigned short)(v3 >> 16));
    }
    for (; i < end; i += 2) {
        unsigned int v0 = h[(size_t)i * 64 + l];
        ax += bf2f((unsigned short)(v0 & 0xffff));
        ay += bf2f((unsigned short)(v0 >> 16));
    }

    __shared__ float red[4][128];
    __shared__ float zin[256];
    __shared__ float zmid[64];
    red[w][2 * l] = ax;
    red[w][2 * l + 1] = ay;
    __syncthreads();
    int mat = t >> 7, col = t & 127;
    zin[t] = red[mat * 2][col] + red[mat * 2 + 1][col];
    __syncthreads();
    if (t < 64) {
        float acc = bl1[t];
        #pragma unroll 8
        for (int k = 0; k < 256; k++) acc = fmaf(zin[k], Wl1[k * 64 + t], acc);
        zmid[t] = fmaxf(acc, 0.f);
    }
    __syncthreads();
    if (t < NCLASS) {
        float acc = bl2[t];
        #pragma unroll
        for (int j = 0; j < 64; j++) acc = fmaf(zmid[j], Wl2[j * 10 + t], acc);
        out[g * NCLASS + t] = acc;
    }
}

// ---------------- launch ----------------

extern "C" void kernel_launch(void* const* d_in, const int* in_sizes, int n_in,
                              void* d_out, int out_size, void* d_ws, size_t ws_size,
                              hipStream_t stream) {
    const float* x   = (const float*)d_in[0];
    const int* eidx  = (const int*)d_in[1];
    const int* batch = (const int*)d_in[2];
    const float* W1a = (const float*)d_in[3];
    const float* b1a = (const float*)d_in[4];
    const float* g1  = (const float*)d_in[5];
    const float* be1 = (const float*)d_in[6];
    const float* m1  = (const float*)d_in[7];
    const float* v1  = (const float*)d_in[8];
    const float* W1b = (const float*)d_in[9];
    const float* b1b = (const float*)d_in[10];
    const float* W2a = (const float*)d_in[11];
    const float* b2a = (const float*)d_in[12];
    const float* g2  = (const float*)d_in[13];
    const float* be2 = (const float*)d_in[14];
    const float* m2  = (const float*)d_in[15];
    const float* v2  = (const float*)d_in[16];
    const float* W2b = (const float*)d_in[17];
    const float* b2b = (const float*)d_in[18];
    const float* Wl1 = (const float*)d_in[19];
    const float* bl1 = (const float*)d_in[20];
    const float* Wl2 = (const float*)d_in[21];
    const float* bl2 = (const float*)d_in[22];
    const int* srcv = eidx;            // edge_index row 0
    const int* dstv = eidx + N_EDGES;  // edge_index row 1

    char* ws = (char*)d_ws;
    size_t off = 0;
    auto alloc = [&](size_t bytes) -> void* {
        void* p = ws + off;
        off = (off + bytes + 255) & ~(size_t)255;
        return p;
    };
    int* cnt      = (int*)alloc(sizeof(int) * N_NODES);
    int* adj      = (int*)alloc(sizeof(int) * (size_t)N_NODES * KSTRIDE);
    float* ep     = (float*)alloc(sizeof(float) * 768);
    unsigned short* wpack = (unsigned short*)alloc(sizeof(unsigned short) * 4 * 16384);
    unsigned short* xb    = (unsigned short*)alloc(sizeof(unsigned short) * (size_t)N_NODES * HDIM);
    unsigned short* bufA  = (unsigned short*)alloc(sizeof(unsigned short) * (size_t)N_NODES * HDIM);
    unsigned short* bufB  = (unsigned short*)alloc(sizeof(unsigned short) * (size_t)N_NODES * HDIM);
    unsigned short* bufC  = (unsigned short*)alloc(sizeof(unsigned short) * (size_t)N_NODES * HDIM);
    (void)ws_size; (void)in_sizes; (void)n_in; (void)out_size;

    float* outp = (float*)d_out;

    k_setup<<<dim3(NB_SETUP), dim3(256), 0, stream>>>(
        x, xb, cnt, W1a, W1b, W2a, W2b, wpack,
        b1a, g1, be1, m1, v1, b1b, b2a, g2, be2, m2, v2, b2b, ep);
    k_scatter<<<dim3((N_EDGES + 255) / 256), dim3(256), 0, stream>>>(srcv, dstv, cnt, adj, N_EDGES);

    dim3 agrid((N_NODES * 16 + 255) / 256), ablk(256);
    dim3 mgrid((N_NODES + 63) / 64), mblk(256);

    // conv1: agg(xb) -> bufA; MLP -> h1 (bufC)
    k_agg<<<agrid, ablk, 0, stream>>>(xb, cnt, adj, bufA);
    k_mlp<<<mgrid, mblk, 0, stream>>>(bufA, wpack + 0 * 16384, wpack + 1 * 16384,
                                      ep + 0, ep + 512, bufC, N_NODES);
    // conv2: agg(h1) -> bufA; MLP -> h2 (bufB)
    k_agg<<<agrid, ablk, 0, stream>>>(bufC, cnt, adj, bufA);
    k_mlp<<<mgrid, mblk, 0, stream>>>(bufA, wpack + 2 * 16384, wpack + 3 * 16384,
                                      ep + 256, ep + 640, bufB, N_NODES);
    // pool + head
    k_pool_head<<<dim3(NGRAPH), dim3(256), 0, stream>>>(bufC, bufB, batch, Wl1, bl1, Wl2, bl2, outp);
}

// Round 10
// 241.400 us; speedup vs baseline: 1.0831x; 1.0831x over previous
//
#include <hip/hip_runtime.h>

#define N_NODES 50000
#define N_EDGES 600000
#define HDIM 128
#define NGRAPH 500
#define NCLASS 10
#define BN_EPS 1e-5f
#define KSLOT 64
#define KSTRIDE 72   // u16 slots; 8-slot pad keeps the 8-edge batch loads in-bounds

typedef short short8 __attribute__((ext_vector_type(8)));
typedef unsigned short ushort8v __attribute__((ext_vector_type(8)));
typedef float floatx4 __attribute__((ext_vector_type(4)));

__device__ __forceinline__ float bf2f(unsigned short u) {
    unsigned int v = ((unsigned int)u) << 16;
    return __uint_as_float(v);
}
__device__ __forceinline__ unsigned short f2bf(float f) {
    unsigned int u = __float_as_uint(f);
    unsigned int r = (u + 0x7fffu + ((u >> 16) & 1u)) >> 16;
    return (unsigned short)r;
}

// ---------------- fused setup: castx | zero cnt | prepW | zero pool | prep(ep) ----------------
#define NB_CAST 6250
#define NB_ZERO 196
#define NB_PREPW 256
#define NB_POOLZ 500          // 2 convs x 500 graphs x 128 cols = 128000 floats
#define NB_SETUP (NB_CAST + NB_ZERO + NB_PREPW + NB_POOLZ + 1)

// W packs (4 x 16384 bf16), frag index: (((ct*4+s)*4+q)*16+m)*8+j
//  w=0 (W1a) / w=2 (W2a): A-operand pack, k = s*32+q*8+j,            val = W[k][n]
//  w=1 (W1b) / w=3 (W2b): B-operand pack, k = pi(s,q,j),             val = W[k][n] (*s2[k] for w=3)
// pi(s,q,j) = (s*2+(j>>2))*16 + q*4 + (j&3)
__global__ void k_setup(const float* __restrict__ x, unsigned short* __restrict__ xb,
                        int* __restrict__ cnt, float* __restrict__ pool,
                        const float* __restrict__ W1a, const float* __restrict__ W1b,
                        const float* __restrict__ W2a, const float* __restrict__ W2b,
                        unsigned short* __restrict__ wpack,
                        const float* __restrict__ b1a, const float* __restrict__ g1,
                        const float* __restrict__ be1, const float* __restrict__ m1,
                        const float* __restrict__ v1, const float* __restrict__ b1b,
                        const float* __restrict__ b2a, const float* __restrict__ g2,
                        const float* __restrict__ be2, const float* __restrict__ m2,
                        const float* __restrict__ v2, const float* __restrict__ b2b,
                        float* __restrict__ ep) {
    int b = blockIdx.x;
    int t = threadIdx.x;
    if (b < NB_CAST) {
        int i = b * 256 + t;   // over 1.6M float4
        float4 v = ((const float4*)x)[i];
        ushort4 o;
        o.x = f2bf(v.x); o.y = f2bf(v.y); o.z = f2bf(v.z); o.w = f2bf(v.w);
        ((ushort4*)xb)[i] = o;
        return;
    }
    b -= NB_CAST;
    if (b < NB_ZERO) {
        int i = b * 256 + t;
        if (i < N_NODES) cnt[i] = 0;
        return;
    }
    b -= NB_ZERO;
    if (b < NB_PREPW) {
        int e = b * 256 + t;               // 0..65535
        int w = e >> 14;
        int s_ = e & 16383;
        int j = s_ & 7;
        int m = (s_ >> 3) & 15;
        int q = (s_ >> 7) & 3;
        int ks = (s_ >> 9) & 3;
        int ct = (s_ >> 11) & 7;
        int n = ct * 16 + m;
        int k;
        float scale = 1.f;
        if (w == 0 || w == 2) {
            k = ks * 32 + q * 8 + j;
        } else {
            k = (ks * 2 + (j >> 2)) * 16 + q * 4 + (j & 3);
            if (w == 3) scale = g2[k] * rsqrtf(v2[k] + BN_EPS);
        }
        const float* W = (w == 0) ? W1a : (w == 1) ? W1b : (w == 2) ? W2a : W2b;
        wpack[e] = f2bf(W[k * 128 + n] * scale);
        return;
    }
    b -= NB_PREPW;
    if (b < NB_POOLZ) {
        int i = b * 256 + t;               // 0..127999
        pool[i] = 0.f;
        return;
    }
    // ep layout: epi[conv][{P,Q}][128] at conv*256, epf[conv][128] at 512+conv*128
    if (t < 128) {
        int j = t;
        float s1 = g1[j] * rsqrtf(v1[j] + BN_EPS);
        ep[0 * 256 + 0 + j]   = s1;
        ep[0 * 256 + 128 + j] = (b1a[j] - m1[j]) * s1 + be1[j];
        ep[1 * 256 + 0 + j]   = 1.f;
        ep[1 * 256 + 128 + j] = b2a[j];
        ep[512 + j] = b1b[j];
        float acc = b2b[j];
        for (int k = 0; k < 128; k++) {
            float s2k = g2[k] * rsqrtf(v2[k] + BN_EPS);
            acc += (be2[k] - m2[k] * s2k) * W2b[k * 128 + j];
        }
        ep[512 + 128 + j] = acc;
    }
}

// ---------------- slot-CSR scatter (u16): adj[dst*KSTRIDE+pos] = src ----------------
__global__ void k_scatter(const int* __restrict__ src, const int* __restrict__ dst,
                          int* __restrict__ cnt, unsigned short* __restrict__ adj, int e) {
    int i = blockIdx.x * blockDim.x + threadIdx.x;
    if (i < e) {
        int d = dst[i];
        int p = atomicAdd(&cnt[d], 1);
        if (p < KSLOT) adj[d * KSTRIDE + p] = (unsigned short)src[i];
    }
}

// ---------------- aggregation: out[i] = x[i] + sum_{j->i} x[j] ----------------
// 16 lanes/node, 4 nodes/wave, 3125 blocks (queue-limited regime: ~32 waves/CU
// resident, 8 x 16B row gathers in flight per lane). u16 indices: one 16B load
// per 8-edge batch; slots >= len clamp to self (L1-hot), over-count removed once.
__global__ __launch_bounds__(256) void k_agg(const unsigned short* __restrict__ x,
                                             const int* __restrict__ cnt,
                                             const unsigned short* __restrict__ adj,
                                             unsigned short* __restrict__ out) {
    int g = blockIdx.x * 256 + threadIdx.x;
    int node = g >> 4;
    int m = g & 15;
    if (node >= N_NODES) return;

    int len = cnt[node];
    if (len > KSLOT) len = KSLOT;
    const unsigned short* ad = adj + node * KSTRIDE;

    ushort8v ra = *(const ushort8v*)(ad);   // first batch's 8 indices (16B)

    float self[8];
    {
        short8 sv = *(const short8*)(x + (size_t)node * 128 + m * 8);
        #pragma unroll
        for (int j = 0; j < 8; j++) self[j] = bf2f((unsigned short)sv[j]);
    }
    float acc[8];
    #pragma unroll
    for (int j = 0; j < 8; j++) acc[j] = self[j];

    int nb = (len + 7) >> 3;     // full batches, clamped slots
    for (int b = 0; b < nb; b++) {
        int i = b * 8;
        ushort8v na = *(const ushort8v*)(ad + i + 8);   // prefetch next (pad keeps in-bounds)
        int u0 = (i + 0 < len) ? (int)ra[0] : node;
        int u1 = (i + 1 < len) ? (int)ra[1] : node;
        int u2 = (i + 2 < len) ? (int)ra[2] : node;
        int u3 = (i + 3 < len) ? (int)ra[3] : node;
        int u4 = (i + 4 < len) ? (int)ra[4] : node;
        int u5 = (i + 5 < len) ? (int)ra[5] : node;
        int u6 = (i + 6 < len) ? (int)ra[6] : node;
        int u7 = (i + 7 < len) ? (int)ra[7] : node;
        short8 f0 = *(const short8*)(x + (size_t)u0 * 128 + m * 8);
        short8 f1 = *(const short8*)(x + (size_t)u1 * 128 + m * 8);
        short8 f2 = *(const short8*)(x + (size_t)u2 * 128 + m * 8);
        short8 f3 = *(const short8*)(x + (size_t)u3 * 128 + m * 8);
        short8 f4 = *(const short8*)(x + (size_t)u4 * 128 + m * 8);
        short8 f5 = *(const short8*)(x + (size_t)u5 * 128 + m * 8);
        short8 f6 = *(const short8*)(x + (size_t)u6 * 128 + m * 8);
        short8 f7 = *(const short8*)(x + (size_t)u7 * 128 + m * 8);
        #pragma unroll
        for (int j = 0; j < 8; j++) {
            float a = bf2f((unsigned short)f0[j]) + bf2f((unsigned short)f1[j]) +
                      bf2f((unsigned short)f2[j]) + bf2f((unsigned short)f3[j]);
            float c = bf2f((unsigned short)f4[j]) + bf2f((unsigned short)f5[j]) +
                      bf2f((unsigned short)f6[j]) + bf2f((unsigned short)f7[j]);
            acc[j] += a + c;
        }
        ra = na;
    }
    float extra = (float)(nb * 8 - len);
    #pragma unroll
    for (int j = 0; j < 8; j++) acc[j] -= extra * self[j];

    short8 r;
    #pragma unroll
    for (int j = 0; j < 8; j++) r[j] = (short)f2bf(acc[j]);
    *(short8*)(out + (size_t)node * 128 + m * 8) = r;
}

// ---------------- fused MLP + pooling ----------------
// Out = relu(relu(A@Wa *P+Q) @ Wb + Qf); per-graph column sums of Out accumulated
// into pool[g*256 + colOff + col] via LDS block-reduction + atomics (batch sorted,
// a 64-row block spans ~1-2 graphs). Out store optional (h2's only consumer is pooling).
__global__ __launch_bounds__(256, 4) void k_mlp(const unsigned short* __restrict__ A,
                                                const unsigned short* __restrict__ WaP,
                                                const unsigned short* __restrict__ WbP,
                                                const float* __restrict__ epi,   // P[128],Q[128]
                                                const float* __restrict__ epf,   // Qf[128]
                                                const int* __restrict__ batch,
                                                float* __restrict__ poolc,       // pool + colOff
                                                unsigned short* __restrict__ Out, int n) {
    __shared__ float ps[16][132];
    int t = threadIdx.x;
    int lane = t & 63;
    int w = t >> 6;
    int q = lane >> 4;
    int m = lane & 15;

    int rowbase0 = blockIdx.x * 64;
    int base = rowbase0 + w * 16;
    int node = base + m;
    if (node >= n) node = n - 1;

    short8 a1[4];
    #pragma unroll
    for (int s = 0; s < 4; s++)
        a1[s] = *(const short8*)(A + (size_t)node * 128 + s * 32 + q * 8);

    int lbase = lane * 8;

    // gemm1 (swapped): acc1[ct] over feature tiles
    floatx4 acc1[8];
    #pragma unroll
    for (int c = 0; c < 8; c++) acc1[c] = (floatx4)0.f;
    #pragma unroll
    for (int s = 0; s < 4; s++) {
        #pragma unroll
        for (int ct = 0; ct < 8; ct++) {
            short8 wf = *(const short8*)(WaP + (ct * 4 + s) * 512 + lbase);
            acc1[ct] = __builtin_amdgcn_mfma_f32_16x16x32_bf16(wf, a1[s], acc1[ct], 0, 0, 0);
        }
    }

    // inter-epilogue + repack into gemm2 A-frags (pure per-lane)
    short8 a2[4];
    #pragma unroll
    for (int s = 0; s < 4; s++) {
        #pragma unroll
        for (int j = 0; j < 8; j++) {
            int ct = s * 2 + (j >> 2);
            int r = j & 3;
            int col = ct * 16 + q * 4 + r;
            float P = epi[col], Q = epi[128 + col];
            float v = fmaxf(fmaf(acc1[ct][r], P, Q), 0.f);
            a2[s][j] = (short)f2bf(v);
        }
    }

    // gemm2 (standard): D rows = nodes (q*4+r), cols = features (lane&15)
    floatx4 acc2[8];
    #pragma unroll
    for (int c = 0; c < 8; c++) acc2[c] = (floatx4)0.f;
    #pragma unroll
    for (int s = 0; s < 4; s++) {
        #pragma unroll
        for (int ct = 0; ct < 8; ct++) {
            short8 wf = *(const short8*)(WbP + (ct * 4 + s) * 512 + lbase);
            acc2[ct] = __builtin_amdgcn_mfma_f32_16x16x32_bf16(a2[s], wf, acc2[ct], 0, 0, 0);
        }
    }

    // final epilogue in-place: acc2 = relu(acc2 + Qf)
    #pragma unroll
    for (int ct = 0; ct < 8; ct++) {
        float Qf = epf[ct * 16 + m];
        #pragma unroll
        for (int r = 0; r < 4; r++) acc2[ct][r] = fmaxf(acc2[ct][r] + Qf, 0.f);
    }

    // optional store (h1 yes; h2 no - pooling is its only consumer)
    if (Out) {
        #pragma unroll
        for (int ct = 0; ct < 8; ct++) {
            int col = ct * 16 + m;
            #pragma unroll
            for (int r = 0; r < 4; r++) {
                int gr = base + q * 4 + r;
                if (gr < n)
                    Out[(size_t)gr * 128 + col] = f2bf(acc2[ct][r]);
            }
        }
    }

    // pooling: per-graph column sums over this block's 64 rows
    int mygid[4];
    #pragma unroll
    for (int r = 0; r < 4; r++) {
        int gr = base + q * 4 + r;
        mygid[r] = (gr < n) ? batch[gr] : -1;
    }
    int lastrow = rowbase0 + 63;
    if (lastrow > n - 1) lastrow = n - 1;
    int g0 = batch[rowbase0];
    int g1 = batch[lastrow];
    for (int g = g0; g <= g1; g++) {
        float pv[8];
        #pragma unroll
        for (int ct = 0; ct < 8; ct++) pv[ct] = 0.f;
        #pragma unroll
        for (int r = 0; r < 4; r++) {
            if (mygid[r] == g) {
                #pragma unroll
                for (int ct = 0; ct < 8; ct++) pv[ct] += acc2[ct][r];
            }
        }
        #pragma unroll
        for (int ct = 0; ct < 8; ct++) ps[w * 4 + q][ct * 16 + m] = pv[ct];
        __syncthreads();
        if (t < 128) {
            float s = 0.f;
            #pragma unroll
            for (int k = 0; k < 16; k++) s += ps[k][t];
            atomicAdd(&poolc[g * 256 + t], s);
        }
        __syncthreads();
    }
}

// ---------------- head: out[g] = relu(z @ Wl1 + bl1) @ Wl2 + bl2, z = pool[g] ----------------
__global__ void k_head(const float* __restrict__ pool, const float* __restrict__ Wl1,
                       const float* __restrict__ bl1, const float* __restrict__ Wl2,
                       const float* __restrict__ bl2, float* __restrict__ out) {
    int g = blockIdx.x;
    int t = threadIdx.x;
    __shared__ float zmid[64];
    const float* z = pool + g * 256;
    float acc = bl1[t];
    #pragma unroll 8
    for (int k = 0; k < 256; k++) acc = fmaf(z[k], Wl1[k * 64 + t], acc);
    zmid[t] = fmaxf(acc, 0.f);
    __syncthreads();
    if (t < NCLASS) {
        float a = bl2[t];
        #pragma unroll
        for (int j = 0; j < 64; j++) a = fmaf(zmid[j], Wl2[j * 10 + t], a);
        out[g * NCLASS + t] = a;
    }
}

// ---------------- launch ----------------

extern "C" void kernel_launch(void* const* d_in, const int* in_sizes, int n_in,
                              void* d_out, int out_size, void* d_ws, size_t ws_size,
                              hipStream_t stream) {
    const float* x   = (const float*)d_in[0];
    const int* eidx  = (const int*)d_in[1];
    const int* batch = (const int*)d_in[2];
    const float* W1a = (const float*)d_in[3];
    const float* b1a = (const float*)d_in[4];
    const float* g1  = (const float*)d_in[5];
    const float* be1 = (const float*)d_in[6];
    const float* m1  = (const float*)d_in[7];
    const float* v1  = (const float*)d_in[8];
    const float* W1b = (const float*)d_in[9];
    const float* b1b = (const float*)d_in[10];
    const float* W2a = (const float*)d_in[11];
    const float* b2a = (const float*)d_in[12];
    const float* g2  = (const float*)d_in[13];
    const float* be2 = (const float*)d_in[14];
    const float* m2  = (const float*)d_in[15];
    const float* v2  = (const float*)d_in[16];
    const float* W2b = (const float*)d_in[17];
    const float* b2b = (const float*)d_in[18];
    const float* Wl1 = (const float*)d_in[19];
    const float* bl1 = (const float*)d_in[20];
    const float* Wl2 = (const float*)d_in[21];
    const float* bl2 = (const float*)d_in[22];
    const int* srcv = eidx;            // edge_index row 0
    const int* dstv = eidx + N_EDGES;  // edge_index row 1

    char* ws = (char*)d_ws;
    size_t off = 0;
    auto alloc = [&](size_t bytes) -> void* {
        void* p = ws + off;
        off = (off + bytes + 255) & ~(size_t)255;
        return p;
    };
    int* cnt      = (int*)alloc(sizeof(int) * N_NODES);
    unsigned short* adj = (unsigned short*)alloc(sizeof(unsigned short) * (size_t)N_NODES * KSTRIDE);
    float* ep     = (float*)alloc(sizeof(float) * 768);
    float* pool   = (float*)alloc(sizeof(float) * NGRAPH * 256);   // [g][0:128]=p1, [128:256]=p2
    unsigned short* wpack = (unsigned short*)alloc(sizeof(unsigned short) * 4 * 16384);
    unsigned short* xb    = (unsigned short*)alloc(sizeof(unsigned short) * (size_t)N_NODES * HDIM);
    unsigned short* bufA  = (unsigned short*)alloc(sizeof(unsigned short) * (size_t)N_NODES * HDIM);
    unsigned short* bufC  = (unsigned short*)alloc(sizeof(unsigned short) * (size_t)N_NODES * HDIM);
    (void)ws_size; (void)in_sizes; (void)n_in; (void)out_size;

    float* outp = (float*)d_out;

    k_setup<<<dim3(NB_SETUP), dim3(256), 0, stream>>>(
        x, xb, cnt, pool, W1a, W1b, W2a, W2b, wpack,
        b1a, g1, be1, m1, v1, b1b, b2a, g2, be2, m2, v2, b2b, ep);
    k_scatter<<<dim3((N_EDGES + 255) / 256), dim3(256), 0, stream>>>(srcv, dstv, cnt, adj, N_EDGES);

    dim3 agrid((N_NODES * 16 + 255) / 256), ablk(256);
    dim3 mgrid((N_NODES + 63) / 64), mblk(256);

    // conv1: agg(xb) -> bufA; MLP(+pool p1) -> h1 (bufC)
    k_agg<<<agrid, ablk, 0, stream>>>(xb, cnt, adj, bufA);
    k_mlp<<<mgrid, mblk, 0, stream>>>(bufA, wpack + 0 * 16384, wpack + 1 * 16384,
                                      ep + 0, ep + 512, batch, pool + 0, bufC, N_NODES);
    // conv2: agg(h1) -> bufA; MLP(+pool p2), no h2 store
    k_agg<<<agrid, ablk, 0, stream>>>(bufC, cnt, adj, bufA);
    k_mlp<<<mgrid, mblk, 0, stream>>>(bufA, wpack + 2 * 16384, wpack + 3 * 16384,
                                      ep + 256, ep + 640, batch, pool + 128, nullptr, N_NODES);
    // head
    k_head<<<dim3(NGRAPH), dim3(64), 0, stream>>>(pool, Wl1, bl1, Wl2, bl2, outp);
}

// Round 11
// 237.882 us; speedup vs baseline: 1.0991x; 1.0148x over previous
//
#include <hip/hip_runtime.h>

#define N_NODES 50000
#define N_EDGES 600000
#define HDIM 128
#define NGRAPH 500
#define NCLASS 10
#define BN_EPS 1e-5f
#define KSLOT 64
#define KSTRIDE 72   // u16 slots; 8-slot pad keeps the 8-edge batch loads in-bounds

typedef short short8 __attribute__((ext_vector_type(8)));
typedef unsigned short ushort8v __attribute__((ext_vector_type(8)));
typedef float floatx4 __attribute__((ext_vector_type(4)));

__device__ __forceinline__ float bf2f(unsigned short u) {
    unsigned int v = ((unsigned int)u) << 16;
    return __uint_as_float(v);
}
__device__ __forceinline__ unsigned short f2bf(float f) {
    unsigned int u = __float_as_uint(f);
    unsigned int r = (u + 0x7fffu + ((u >> 16) & 1u)) >> 16;
    return (unsigned short)r;
}

// ---------------- pre-kernel: zero cnt (must precede the scatter blocks in k_setup) ----
__global__ void k_zero(int* __restrict__ cnt) {
    int i = blockIdx.x * blockDim.x + threadIdx.x;
    if (i < N_NODES) cnt[i] = 0;
}

// ---------------- fused setup: scatter | castx | prepW | zero pool | prep(ep) ----------
#define NB_SCAT 586           // 150000 int4-edge threads
#define NB_CAST 6250
#define NB_PREPW 256
#define NB_POOLZ 500          // 2 convs x 500 graphs x 128 cols = 128000 floats
#define NB_SETUP (NB_SCAT + NB_CAST + NB_PREPW + NB_POOLZ + 1)

// W packs (4 x 16384 bf16), frag index: (((ct*4+s)*4+q)*16+m)*8+j
//  w=0 (W1a) / w=2 (W2a): A-operand pack, k = s*32+q*8+j,            val = W[k][n]
//  w=1 (W1b) / w=3 (W2b): B-operand pack, k = pi(s,q,j),             val = W[k][n] (*s2[k] for w=3)
// pi(s,q,j) = (s*2+(j>>2))*16 + q*4 + (j&3)
__global__ void k_setup(const float* __restrict__ x, unsigned short* __restrict__ xb,
                        const int* __restrict__ src, const int* __restrict__ dst,
                        int* __restrict__ cnt, unsigned short* __restrict__ adj,
                        float* __restrict__ pool,
                        const float* __restrict__ W1a, const float* __restrict__ W1b,
                        const float* __restrict__ W2a, const float* __restrict__ W2b,
                        unsigned short* __restrict__ wpack,
                        const float* __restrict__ b1a, const float* __restrict__ g1,
                        const float* __restrict__ be1, const float* __restrict__ m1,
                        const float* __restrict__ v1, const float* __restrict__ b1b,
                        const float* __restrict__ b2a, const float* __restrict__ g2,
                        const float* __restrict__ be2, const float* __restrict__ m2,
                        const float* __restrict__ v2, const float* __restrict__ b2b,
                        float* __restrict__ ep) {
    int b = blockIdx.x;
    int t = threadIdx.x;
    if (b < NB_SCAT) {
        int i4 = b * 256 + t;              // 4 edges per thread
        if (i4 < N_EDGES / 4) {
            int4 s4 = ((const int4*)src)[i4];
            int4 d4 = ((const int4*)dst)[i4];
            int p;
            p = atomicAdd(&cnt[d4.x], 1); if (p < KSLOT) adj[d4.x * KSTRIDE + p] = (unsigned short)s4.x;
            p = atomicAdd(&cnt[d4.y], 1); if (p < KSLOT) adj[d4.y * KSTRIDE + p] = (unsigned short)s4.y;
            p = atomicAdd(&cnt[d4.z], 1); if (p < KSLOT) adj[d4.z * KSTRIDE + p] = (unsigned short)s4.z;
            p = atomicAdd(&cnt[d4.w], 1); if (p < KSLOT) adj[d4.w * KSTRIDE + p] = (unsigned short)s4.w;
        }
        return;
    }
    b -= NB_SCAT;
    if (b < NB_CAST) {
        int i = b * 256 + t;   // over 1.6M float4
        float4 v = ((const float4*)x)[i];
        ushort4 o;
        o.x = f2bf(v.x); o.y = f2bf(v.y); o.z = f2bf(v.z); o.w = f2bf(v.w);
        ((ushort4*)xb)[i] = o;
        return;
    }
    b -= NB_CAST;
    if (b < NB_PREPW) {
        int e = b * 256 + t;               // 0..65535
        int w = e >> 14;
        int s_ = e & 16383;
        int j = s_ & 7;
        int m = (s_ >> 3) & 15;
        int q = (s_ >> 7) & 3;
        int ks = (s_ >> 9) & 3;
        int ct = (s_ >> 11) & 7;
        int n = ct * 16 + m;
        int k;
        float scale = 1.f;
        if (w == 0 || w == 2) {
            k = ks * 32 + q * 8 + j;
        } else {
            k = (ks * 2 + (j >> 2)) * 16 + q * 4 + (j & 3);
            if (w == 3) scale = g2[k] * rsqrtf(v2[k] + BN_EPS);
        }
        const float* W = (w == 0) ? W1a : (w == 1) ? W1b : (w == 2) ? W2a : W2b;
        wpack[e] = f2bf(W[k * 128 + n] * scale);
        return;
    }
    b -= NB_PREPW;
    if (b < NB_POOLZ) {
        int i = b * 256 + t;               // 0..127999
        pool[i] = 0.f;
        return;
    }
    // ep layout: epi[conv][{P,Q}][128] at conv*256, epf[conv][128] at 512+conv*128
    if (t < 128) {
        int j = t;
        float s1 = g1[j] * rsqrtf(v1[j] + BN_EPS);
        ep[0 * 256 + 0 + j]   = s1;
        ep[0 * 256 + 128 + j] = (b1a[j] - m1[j]) * s1 + be1[j];
        ep[1 * 256 + 0 + j]   = 1.f;
        ep[1 * 256 + 128 + j] = b2a[j];
        ep[512 + j] = b1b[j];
        float acc = b2b[j];
        for (int k = 0; k < 128; k++) {
            float s2k = g2[k] * rsqrtf(v2[k] + BN_EPS);
            acc += (be2[k] - m2[k] * s2k) * W2b[k * 128 + j];
        }
        ep[512 + 128 + j] = acc;
    }
}

// ---------------- aggregation: out[i] = x[i] + sum_{j->i} x[j] ----------------
// 16 lanes/node, 4 nodes/wave, 3125 blocks (queue-limited regime: ~32 waves/CU
// resident, 8 x 16B row gathers in flight per lane). u16 indices: one 16B load
// per 8-edge batch; slots >= len clamp to self (L1-hot), over-count removed once.
__global__ __launch_bounds__(256) void k_agg(const unsigned short* __restrict__ x,
                                             const int* __restrict__ cnt,
                                             const unsigned short* __restrict__ adj,
                                             unsigned short* __restrict__ out) {
    int g = blockIdx.x * 256 + threadIdx.x;
    int node = g >> 4;
    int m = g & 15;
    if (node >= N_NODES) return;

    int len = cnt[node];
    if (len > KSLOT) len = KSLOT;
    const unsigned short* ad = adj + node * KSTRIDE;

    ushort8v ra = *(const ushort8v*)(ad);   // first batch's 8 indices (16B)

    float self[8];
    {
        short8 sv = *(const short8*)(x + (size_t)node * 128 + m * 8);
        #pragma unroll
        for (int j = 0; j < 8; j++) self[j] = bf2f((unsigned short)sv[j]);
    }
    float acc[8];
    #pragma unroll
    for (int j = 0; j < 8; j++) acc[j] = self[j];

    int nb = (len + 7) >> 3;     // full batches, clamped slots
    for (int b = 0; b < nb; b++) {
        int i = b * 8;
        ushort8v na = *(const ushort8v*)(ad + i + 8);   // prefetch next (pad keeps in-bounds)
        int u0 = (i + 0 < len) ? (int)ra[0] : node;
        int u1 = (i + 1 < len) ? (int)ra[1] : node;
        int u2 = (i + 2 < len) ? (int)ra[2] : node;
        int u3 = (i + 3 < len) ? (int)ra[3] : node;
        int u4 = (i + 4 < len) ? (int)ra[4] : node;
        int u5 = (i + 5 < len) ? (int)ra[5] : node;
        int u6 = (i + 6 < len) ? (int)ra[6] : node;
        int u7 = (i + 7 < len) ? (int)ra[7] : node;
        short8 f0 = *(const short8*)(x + (size_t)u0 * 128 + m * 8);
        short8 f1 = *(const short8*)(x + (size_t)u1 * 128 + m * 8);
        short8 f2 = *(const short8*)(x + (size_t)u2 * 128 + m * 8);
        short8 f3 = *(const short8*)(x + (size_t)u3 * 128 + m * 8);
        short8 f4 = *(const short8*)(x + (size_t)u4 * 128 + m * 8);
        short8 f5 = *(const short8*)(x + (size_t)u5 * 128 + m * 8);
        short8 f6 = *(const short8*)(x + (size_t)u6 * 128 + m * 8);
        short8 f7 = *(const short8*)(x + (size_t)u7 * 128 + m * 8);
        #pragma unroll
        for (int j = 0; j < 8; j++) {
            float a = bf2f((unsigned short)f0[j]) + bf2f((unsigned short)f1[j]) +
                      bf2f((unsigned short)f2[j]) + bf2f((unsigned short)f3[j]);
            float c = bf2f((unsigned short)f4[j]) + bf2f((unsigned short)f5[j]) +
                      bf2f((unsigned short)f6[j]) + bf2f((unsigned short)f7[j]);
            acc[j] += a + c;
        }
        ra = na;
    }
    float extra = (float)(nb * 8 - len);
    #pragma unroll
    for (int j = 0; j < 8; j++) acc[j] -= extra * self[j];

    short8 r;
    #pragma unroll
    for (int j = 0; j < 8; j++) r[j] = (short)f2bf(acc[j]);
    *(short8*)(out + (size_t)node * 128 + m * 8) = r;
}

// ---------------- fused MLP + pooling ----------------
// Out = relu(relu(A@Wa *P+Q) @ Wb + Qf); both W packs staged in 64KB LDS (cuts
// per-CU L2 W traffic 768KB -> 128KB; frag reads become LDS hits). Per-graph
// column sums accumulated into pool via LDS reduction + atomics. Out store
// optional (h2's only consumer is pooling).
__global__ __launch_bounds__(256, 2) void k_mlp(const unsigned short* __restrict__ A,
                                                const unsigned short* __restrict__ WaP,
                                                const unsigned short* __restrict__ WbP,
                                                const float* __restrict__ epi,   // P[128],Q[128]
                                                const float* __restrict__ epf,   // Qf[128]
                                                const int* __restrict__ batch,
                                                float* __restrict__ poolc,       // pool + colOff
                                                unsigned short* __restrict__ Out, int n) {
    __shared__ unsigned short Wl[2][16384];   // 64 KB
    __shared__ float ps[16][132];
    int t = threadIdx.x;
    int lane = t & 63;
    int w = t >> 6;
    int q = lane >> 4;
    int m = lane & 15;

    int rowbase0 = blockIdx.x * 64;
    int base = rowbase0 + w * 16;
    int node = base + m;
    if (node >= n) node = n - 1;

    // A-frag loads first (latency hides under W staging)
    short8 a1[4];
    #pragma unroll
    for (int s = 0; s < 4; s++)
        a1[s] = *(const short8*)(A + (size_t)node * 128 + s * 32 + q * 8);

    // stage both W packs into LDS
    #pragma unroll
    for (int i = 0; i < 8; i++) {
        int c = t + 256 * i;
        *(short8*)(&Wl[0][c * 8]) = *(const short8*)(WaP + c * 8);
        *(short8*)(&Wl[1][c * 8]) = *(const short8*)(WbP + c * 8);
    }
    __syncthreads();

    int lbase = lane * 8;

    // gemm1 (swapped): acc1[ct] over feature tiles
    floatx4 acc1[8];
    #pragma unroll
    for (int c = 0; c < 8; c++) acc1[c] = (floatx4)0.f;
    #pragma unroll
    for (int s = 0; s < 4; s++) {
        #pragma unroll
        for (int ct = 0; ct < 8; ct++) {
            short8 wf = *(const short8*)(&Wl[0][(ct * 4 + s) * 512 + lbase]);
            acc1[ct] = __builtin_amdgcn_mfma_f32_16x16x32_bf16(wf, a1[s], acc1[ct], 0, 0, 0);
        }
    }

    // inter-epilogue + repack into gemm2 A-frags (pure per-lane)
    short8 a2[4];
    #pragma unroll
    for (int s = 0; s < 4; s++) {
        #pragma unroll
        for (int j = 0; j < 8; j++) {
            int ct = s * 2 + (j >> 2);
            int r = j & 3;
            int col = ct * 16 + q * 4 + r;
            float P = epi[col], Q = epi[128 + col];
            float v = fmaxf(fmaf(acc1[ct][r], P, Q), 0.f);
            a2[s][j] = (short)f2bf(v);
        }
    }

    // gemm2 (standard): D rows = nodes (q*4+r), cols = features (lane&15)
    floatx4 acc2[8];
    #pragma unroll
    for (int c = 0; c < 8; c++) acc2[c] = (floatx4)0.f;
    #pragma unroll
    for (int s = 0; s < 4; s++) {
        #pragma unroll
        for (int ct = 0; ct < 8; ct++) {
            short8 wf = *(const short8*)(&Wl[1][(ct * 4 + s) * 512 + lbase]);
            acc2[ct] = __builtin_amdgcn_mfma_f32_16x16x32_bf16(a2[s], wf, acc2[ct], 0, 0, 0);
        }
    }

    // final epilogue in-place: acc2 = relu(acc2 + Qf)
    #pragma unroll
    for (int ct = 0; ct < 8; ct++) {
        float Qf = epf[ct * 16 + m];
        #pragma unroll
        for (int r = 0; r < 4; r++) acc2[ct][r] = fmaxf(acc2[ct][r] + Qf, 0.f);
    }

    // optional store (h1 yes; h2 no - pooling is its only consumer)
    if (Out) {
        #pragma unroll
        for (int ct = 0; ct < 8; ct++) {
            int col = ct * 16 + m;
            #pragma unroll
            for (int r = 0; r < 4; r++) {
                int gr = base + q * 4 + r;
                if (gr < n)
                    Out[(size_t)gr * 128 + col] = f2bf(acc2[ct][r]);
            }
        }
    }

    // pooling: per-graph column sums over this block's 64 rows
    int mygid[4];
    #pragma unroll
    for (int r = 0; r < 4; r++) {
        int gr = base + q * 4 + r;
        mygid[r] = (gr < n) ? batch[gr] : -1;
    }
    int lastrow = rowbase0 + 63;
    if (lastrow > n - 1) lastrow = n - 1;
    int g0 = batch[rowbase0];
    int g1 = batch[lastrow];
    for (int g = g0; g <= g1; g++) {
        float pv[8];
        #pragma unroll
        for (int ct = 0; ct < 8; ct++) pv[ct] = 0.f;
        #pragma unroll
        for (int r = 0; r < 4; r++) {
            if (mygid[r] == g) {
                #pragma unroll
                for (int ct = 0; ct < 8; ct++) pv[ct] += acc2[ct][r];
            }
        }
        #pragma unroll
        for (int ct = 0; ct < 8; ct++) ps[w * 4 + q][ct * 16 + m] = pv[ct];
        __syncthreads();
        if (t < 128) {
            float s = 0.f;
            #pragma unroll
            for (int k = 0; k < 16; k++) s += ps[k][t];
            atomicAdd(&poolc[g * 256 + t], s);
        }
        __syncthreads();
    }
}

// ---------------- head: out[g] = relu(z @ Wl1 + bl1) @ Wl2 + bl2, z = pool[g] ----------------
__global__ void k_head(const float* __restrict__ pool, const float* __restrict__ Wl1,
                       const float* __restrict__ bl1, const float* __restrict__ Wl2,
                       const float* __restrict__ bl2, float* __restrict__ out) {
    int g = blockIdx.x;
    int t = threadIdx.x;
    __shared__ float zmid[64];
    const float* z = pool + g * 256;
    float acc = bl1[t];
    #pragma unroll 8
    for (int k = 0; k < 256; k++) acc = fmaf(z[k], Wl1[k * 64 + t], acc);
    zmid[t] = fmaxf(acc, 0.f);
    __syncthreads();
    if (t < NCLASS) {
        float a = bl2[t];
        #pragma unroll
        for (int j = 0; j < 64; j++) a = fmaf(zmid[j], Wl2[j * 10 + t], a);
        out[g * NCLASS + t] = a;
    }
}

// ---------------- launch ----------------

extern "C" void kernel_launch(void* const* d_in, const int* in_sizes, int n_in,
                              void* d_out, int out_size, void* d_ws, size_t ws_size,
                              hipStream_t stream) {
    const float* x   = (const float*)d_in[0];
    const int* eidx  = (const int*)d_in[1];
    const int* batch = (const int*)d_in[2];
    const float* W1a = (const float*)d_in[3];
    const float* b1a = (const float*)d_in[4];
    const float* g1  = (const float*)d_in[5];
    const float* be1 = (const float*)d_in[6];
    const float* m1  = (const float*)d_in[7];
    const float* v1  = (const float*)d_in[8];
    const float* W1b = (const float*)d_in[9];
    const float* b1b = (const float*)d_in[10];
    const float* W2a = (const float*)d_in[11];
    const float* b2a = (const float*)d_in[12];
    const float* g2  = (const float*)d_in[13];
    const float* be2 = (const float*)d_in[14];
    const float* m2  = (const float*)d_in[15];
    const float* v2  = (const float*)d_in[16];
    const float* W2b = (const float*)d_in[17];
    const float* b2b = (const float*)d_in[18];
    const float* Wl1 = (const float*)d_in[19];
    const float* bl1 = (const float*)d_in[20];
    const float* Wl2 = (const float*)d_in[21];
    const float* bl2 = (const float*)d_in[22];
    const int* srcv = eidx;            // edge_index row 0
    const int* dstv = eidx + N_EDGES;  // edge_index row 1

    char* ws = (char*)d_ws;
    size_t off = 0;
    auto alloc = [&](size_t bytes) -> void* {
        void* p = ws + off;
        off = (off + bytes + 255) & ~(size_t)255;
        return p;
    };
    int* cnt      = (int*)alloc(sizeof(int) * N_NODES);
    unsigned short* adj = (unsigned short*)alloc(sizeof(unsigned short) * (size_t)N_NODES * KSTRIDE);
    float* ep     = (float*)alloc(sizeof(float) * 768);
    float* pool   = (float*)alloc(sizeof(float) * NGRAPH * 256);   // [g][0:128]=p1, [128:256]=p2
    unsigned short* wpack = (unsigned short*)alloc(sizeof(unsigned short) * 4 * 16384);
    unsigned short* xb    = (unsigned short*)alloc(sizeof(unsigned short) * (size_t)N_NODES * HDIM);
    unsigned short* bufA  = (unsigned short*)alloc(sizeof(unsigned short) * (size_t)N_NODES * HDIM);
    unsigned short* bufC  = (unsigned short*)alloc(sizeof(unsigned short) * (size_t)N_NODES * HDIM);
    (void)ws_size; (void)in_sizes; (void)n_in; (void)out_size;

    float* outp = (float*)d_out;

    // zero cnt first (scatter inside k_setup depends on it)
    k_zero<<<dim3((N_NODES + 255) / 256), dim3(256), 0, stream>>>(cnt);
    // setup mega-kernel: scatter | cast | prepW | poolz | ep
    k_setup<<<dim3(NB_SETUP), dim3(256), 0, stream>>>(
        x, xb, srcv, dstv, cnt, adj, pool, W1a, W1b, W2a, W2b, wpack,
        b1a, g1, be1, m1, v1, b1b, b2a, g2, be2, m2, v2, b2b, ep);

    dim3 agrid((N_NODES * 16 + 255) / 256), ablk(256);
    dim3 mgrid((N_NODES + 63) / 64), mblk(256);

    // conv1: agg(xb) -> bufA; MLP(+pool p1) -> h1 (bufC)
    k_agg<<<agrid, ablk, 0, stream>>>(xb, cnt, adj, bufA);
    k_mlp<<<mgrid, mblk, 0, stream>>>(bufA, wpack + 0 * 16384, wpack + 1 * 16384,
                                      ep + 0, ep + 512, batch, pool + 0, bufC, N_NODES);
    // conv2: agg(h1) -> bufA; MLP(+pool p2), no h2 store
    k_agg<<<agrid, ablk, 0, stream>>>(bufC, cnt, adj, bufA);
    k_mlp<<<mgrid, mblk, 0, stream>>>(bufA, wpack + 2 * 16384, wpack + 3 * 16384,
                                      ep + 256, ep + 640, batch, pool + 128, nullptr, N_NODES);
    // head
    k_head<<<dim3(NGRAPH), dim3(64), 0, stream>>>(pool, Wl1, bl1, Wl2, bl2, outp);
}

// Round 12
// 227.799 us; speedup vs baseline: 1.1478x; 1.0443x over previous
//
#include <hip/hip_runtime.h>

#define N_NODES 50000
#define N_EDGES 600000
#define HDIM 128
#define NGRAPH 500
#define NCLASS 10
#define BN_EPS 1e-5f
#define KSLOT 64
#define KSTRIDE 72   // u16 slots; 8-slot pad keeps the 8-edge batch loads in-bounds

typedef short short8 __attribute__((ext_vector_type(8)));
typedef unsigned short ushort8v __attribute__((ext_vector_type(8)));
typedef float floatx4 __attribute__((ext_vector_type(4)));

__device__ __forceinline__ float bf2f(unsigned short u) {
    unsigned int v = ((unsigned int)u) << 16;
    return __uint_as_float(v);
}
__device__ __forceinline__ unsigned short f2bf(float f) {
    unsigned int u = __float_as_uint(f);
    unsigned int r = (u + 0x7fffu + ((u >> 16) & 1u)) >> 16;
    return (unsigned short)r;
}

// ---------------- pre-kernel: zero cnt (must precede the scatter blocks in k_setup) ----
__global__ void k_zero(int* __restrict__ cnt) {
    int i = blockIdx.x * blockDim.x + threadIdx.x;
    if (i < N_NODES) cnt[i] = 0;
}

// ---------------- fused setup: scatter (interleaved) | castx | prepW | zero pool | ep ----
// Scatter blocks are every ILV-th block so their latency-bound atomics spread across
// all CUs and overlap the streaming roles (head-of-grid placement serialized them).
#define ILV 13
#define NB_SCAT 586           // 150000 int4-edge threads
#define NB_CAST 6250
#define NB_PREPW 256
#define NB_POOLZ 500          // 2 convs x 500 graphs x 128 cols = 128000 floats
#define NB_SETUP (NB_SCAT * ILV)   // 7618; non-scatter ranks cover 7032 >= 7007 used

// W packs (4 x 16384 bf16), frag index: (((ct*4+s)*4+q)*16+m)*8+j
//  w=0 (W1a) / w=2 (W2a): A-operand pack, k = s*32+q*8+j,            val = W[k][n]
//  w=1 (W1b) / w=3 (W2b): B-operand pack, k = pi(s,q,j),             val = W[k][n] (*s2[k] for w=3)
// pi(s,q,j) = (s*2+(j>>2))*16 + q*4 + (j&3)
__global__ void k_setup(const float* __restrict__ x, unsigned short* __restrict__ xb,
                        const int* __restrict__ src, const int* __restrict__ dst,
                        int* __restrict__ cnt, unsigned short* __restrict__ adj,
                        float* __restrict__ pool,
                        const float* __restrict__ W1a, const float* __restrict__ W1b,
                        const float* __restrict__ W2a, const float* __restrict__ W2b,
                        unsigned short* __restrict__ wpack,
                        const float* __restrict__ b1a, const float* __restrict__ g1,
                        const float* __restrict__ be1, const float* __restrict__ m1,
                        const float* __restrict__ v1, const float* __restrict__ b1b,
                        const float* __restrict__ b2a, const float* __restrict__ g2,
                        const float* __restrict__ be2, const float* __restrict__ m2,
                        const float* __restrict__ v2, const float* __restrict__ b2b,
                        float* __restrict__ ep) {
    int b = blockIdx.x;
    int t = threadIdx.x;
    if (b % ILV == 0) {
        int i4 = (b / ILV) * 256 + t;      // 4 edges per thread
        if (i4 < N_EDGES / 4) {
            int4 s4 = ((const int4*)src)[i4];
            int4 d4 = ((const int4*)dst)[i4];
            int p;
            p = atomicAdd(&cnt[d4.x], 1); if (p < KSLOT) adj[d4.x * KSTRIDE + p] = (unsigned short)s4.x;
            p = atomicAdd(&cnt[d4.y], 1); if (p < KSLOT) adj[d4.y * KSTRIDE + p] = (unsigned short)s4.y;
            p = atomicAdd(&cnt[d4.z], 1); if (p < KSLOT) adj[d4.z * KSTRIDE + p] = (unsigned short)s4.z;
            p = atomicAdd(&cnt[d4.w], 1); if (p < KSLOT) adj[d4.w * KSTRIDE + p] = (unsigned short)s4.w;
        }
        return;
    }
    b = b - b / ILV - 1;                   // non-scatter rank
    if (b < NB_CAST) {
        int i = b * 256 + t;   // over 1.6M float4
        float4 v = ((const float4*)x)[i];
        ushort4 o;
        o.x = f2bf(v.x); o.y = f2bf(v.y); o.z = f2bf(v.z); o.w = f2bf(v.w);
        ((ushort4*)xb)[i] = o;
        return;
    }
    b -= NB_CAST;
    if (b < NB_PREPW) {
        int e = b * 256 + t;               // 0..65535
        int w = e >> 14;
        int s_ = e & 16383;
        int j = s_ & 7;
        int m = (s_ >> 3) & 15;
        int q = (s_ >> 7) & 3;
        int ks = (s_ >> 9) & 3;
        int ct = (s_ >> 11) & 7;
        int n = ct * 16 + m;
        int k;
        float scale = 1.f;
        if (w == 0 || w == 2) {
            k = ks * 32 + q * 8 + j;
        } else {
            k = (ks * 2 + (j >> 2)) * 16 + q * 4 + (j & 3);
            if (w == 3) scale = g2[k] * rsqrtf(v2[k] + BN_EPS);
        }
        const float* W = (w == 0) ? W1a : (w == 1) ? W1b : (w == 2) ? W2a : W2b;
        wpack[e] = f2bf(W[k * 128 + n] * scale);
        return;
    }
    b -= NB_PREPW;
    if (b < NB_POOLZ) {
        int i = b * 256 + t;               // 0..127999
        pool[i] = 0.f;
        return;
    }
    b -= NB_POOLZ;
    if (b != 0) return;
    // ep layout: epi[conv][{P,Q}][128] at conv*256, epf[conv][128] at 512+conv*128
    if (t < 128) {
        int j = t;
        float s1 = g1[j] * rsqrtf(v1[j] + BN_EPS);
        ep[0 * 256 + 0 + j]   = s1;
        ep[0 * 256 + 128 + j] = (b1a[j] - m1[j]) * s1 + be1[j];
        ep[1 * 256 + 0 + j]   = 1.f;
        ep[1 * 256 + 128 + j] = b2a[j];
        ep[512 + j] = b1b[j];
        float acc = b2b[j];
        for (int k = 0; k < 128; k++) {
            float s2k = g2[k] * rsqrtf(v2[k] + BN_EPS);
            acc += (be2[k] - m2[k] * s2k) * W2b[k * 128 + j];
        }
        ep[512 + 128 + j] = acc;
    }
}

// ---------------- aggregation: out[i] = x[i] + sum_{j->i} x[j] ----------------
// 16 lanes/node, 4 nodes/wave, 3125 blocks (queue-limited regime: ~32 waves/CU
// resident, 8 x 16B row gathers in flight per lane). u16 indices: one 16B load
// per 8-edge batch; slots >= len clamp to self (L1-hot), over-count removed once.
__global__ __launch_bounds__(256) void k_agg(const unsigned short* __restrict__ x,
                                             const int* __restrict__ cnt,
                                             const unsigned short* __restrict__ adj,
                                             unsigned short* __restrict__ out) {
    int g = blockIdx.x * 256 + threadIdx.x;
    int node = g >> 4;
    int m = g & 15;
    if (node >= N_NODES) return;

    int len = cnt[node];
    if (len > KSLOT) len = KSLOT;
    const unsigned short* ad = adj + node * KSTRIDE;

    ushort8v ra = *(const ushort8v*)(ad);   // first batch's 8 indices (16B)

    float self[8];
    {
        short8 sv = *(const short8*)(x + (size_t)node * 128 + m * 8);
        #pragma unroll
        for (int j = 0; j < 8; j++) self[j] = bf2f((unsigned short)sv[j]);
    }
    float acc[8];
    #pragma unroll
    for (int j = 0; j < 8; j++) acc[j] = self[j];

    int nb = (len + 7) >> 3;     // full batches, clamped slots
    for (int b = 0; b < nb; b++) {
        int i = b * 8;
        ushort8v na = *(const ushort8v*)(ad + i + 8);   // prefetch next (pad keeps in-bounds)
        int u0 = (i + 0 < len) ? (int)ra[0] : node;
        int u1 = (i + 1 < len) ? (int)ra[1] : node;
        int u2 = (i + 2 < len) ? (int)ra[2] : node;
        int u3 = (i + 3 < len) ? (int)ra[3] : node;
        int u4 = (i + 4 < len) ? (int)ra[4] : node;
        int u5 = (i + 5 < len) ? (int)ra[5] : node;
        int u6 = (i + 6 < len) ? (int)ra[6] : node;
        int u7 = (i + 7 < len) ? (int)ra[7] : node;
        short8 f0 = *(const short8*)(x + (size_t)u0 * 128 + m * 8);
        short8 f1 = *(const short8*)(x + (size_t)u1 * 128 + m * 8);
        short8 f2 = *(const short8*)(x + (size_t)u2 * 128 + m * 8);
        short8 f3 = *(const short8*)(x + (size_t)u3 * 128 + m * 8);
        short8 f4 = *(const short8*)(x + (size_t)u4 * 128 + m * 8);
        short8 f5 = *(const short8*)(x + (size_t)u5 * 128 + m * 8);
        short8 f6 = *(const short8*)(x + (size_t)u6 * 128 + m * 8);
        short8 f7 = *(const short8*)(x + (size_t)u7 * 128 + m * 8);
        #pragma unroll
        for (int j = 0; j < 8; j++) {
            float a = bf2f((unsigned short)f0[j]) + bf2f((unsigned short)f1[j]) +
                      bf2f((unsigned short)f2[j]) + bf2f((unsigned short)f3[j]);
            float c = bf2f((unsigned short)f4[j]) + bf2f((unsigned short)f5[j]) +
                      bf2f((unsigned short)f6[j]) + bf2f((unsigned short)f7[j]);
            acc[j] += a + c;
        }
        ra = na;
    }
    float extra = (float)(nb * 8 - len);
    #pragma unroll
    for (int j = 0; j < 8; j++) acc[j] -= extra * self[j];

    short8 r;
    #pragma unroll
    for (int j = 0; j < 8; j++) r[j] = (short)f2bf(acc[j]);
    *(short8*)(out + (size_t)node * 128 + m * 8) = r;
}

// ---------------- fused MLP + pooling ----------------
// Out = relu(relu(A@Wa *P+Q) @ Wb + Qf); both W packs staged in 64KB LDS (cuts
// per-CU L2 W traffic 768KB -> 128KB; frag reads become LDS hits). Per-graph
// column sums accumulated into pool via LDS reduction + atomics. Out store
// optional (h2's only consumer is pooling).
__global__ __launch_bounds__(256, 2) void k_mlp(const unsigned short* __restrict__ A,
                                                const unsigned short* __restrict__ WaP,
                                                const unsigned short* __restrict__ WbP,
                                                const float* __restrict__ epi,   // P[128],Q[128]
                                                const float* __restrict__ epf,   // Qf[128]
                                                const int* __restrict__ batch,
                                                float* __restrict__ poolc,       // pool + colOff
                                                unsigned short* __restrict__ Out, int n) {
    __shared__ unsigned short Wl[2][16384];   // 64 KB
    __shared__ float ps[16][132];
    int t = threadIdx.x;
    int lane = t & 63;
    int w = t >> 6;
    int q = lane >> 4;
    int m = lane & 15;

    int rowbase0 = blockIdx.x * 64;
    int base = rowbase0 + w * 16;
    int node = base + m;
    if (node >= n) node = n - 1;

    // A-frag loads first (latency hides under W staging)
    short8 a1[4];
    #pragma unroll
    for (int s = 0; s < 4; s++)
        a1[s] = *(const short8*)(A + (size_t)node * 128 + s * 32 + q * 8);

    // stage both W packs into LDS
    #pragma unroll
    for (int i = 0; i < 8; i++) {
        int c = t + 256 * i;
        *(short8*)(&Wl[0][c * 8]) = *(const short8*)(WaP + c * 8);
        *(short8*)(&Wl[1][c * 8]) = *(const short8*)(WbP + c * 8);
    }
    __syncthreads();

    int lbase = lane * 8;

    // gemm1 (swapped): acc1[ct] over feature tiles
    floatx4 acc1[8];
    #pragma unroll
    for (int c = 0; c < 8; c++) acc1[c] = (floatx4)0.f;
    #pragma unroll
    for (int s = 0; s < 4; s++) {
        #pragma unroll
        for (int ct = 0; ct < 8; ct++) {
            short8 wf = *(const short8*)(&Wl[0][(ct * 4 + s) * 512 + lbase]);
            acc1[ct] = __builtin_amdgcn_mfma_f32_16x16x32_bf16(wf, a1[s], acc1[ct], 0, 0, 0);
        }
    }

    // inter-epilogue + repack into gemm2 A-frags (pure per-lane)
    short8 a2[4];
    #pragma unroll
    for (int s = 0; s < 4; s++) {
        #pragma unroll
        for (int j = 0; j < 8; j++) {
            int ct = s * 2 + (j >> 2);
            int r = j & 3;
            int col = ct * 16 + q * 4 + r;
            float P = epi[col], Q = epi[128 + col];
            float v = fmaxf(fmaf(acc1[ct][r], P, Q), 0.f);
            a2[s][j] = (short)f2bf(v);
        }
    }

    // gemm2 (standard): D rows = nodes (q*4+r), cols = features (lane&15)
    floatx4 acc2[8];
    #pragma unroll
    for (int c = 0; c < 8; c++) acc2[c] = (floatx4)0.f;
    #pragma unroll
    for (int s = 0; s < 4; s++) {
        #pragma unroll
        for (int ct = 0; ct < 8; ct++) {
            short8 wf = *(const short8*)(&Wl[1][(ct * 4 + s) * 512 + lbase]);
            acc2[ct] = __builtin_amdgcn_mfma_f32_16x16x32_bf16(a2[s], wf, acc2[ct], 0, 0, 0);
        }
    }

    // final epilogue in-place: acc2 = relu(acc2 + Qf)
    #pragma unroll
    for (int ct = 0; ct < 8; ct++) {
        float Qf = epf[ct * 16 + m];
        #pragma unroll
        for (int r = 0; r < 4; r++) acc2[ct][r] = fmaxf(acc2[ct][r] + Qf, 0.f);
    }

    // optional store (h1 yes; h2 no - pooling is its only consumer)
    if (Out) {
        #pragma unroll
        for (int ct = 0; ct < 8; ct++) {
            int col = ct * 16 + m;
            #pragma unroll
            for (int r = 0; r < 4; r++) {
                int gr = base + q * 4 + r;
                if (gr < n)
                    Out[(size_t)gr * 128 + col] = f2bf(acc2[ct][r]);
            }
        }
    }

    // pooling: per-graph column sums over this block's 64 rows
    int mygid[4];
    #pragma unroll
    for (int r = 0; r < 4; r++) {
        int gr = base + q * 4 + r;
        mygid[r] = (gr < n) ? batch[gr] : -1;
    }
    int lastrow = rowbase0 + 63;
    if (lastrow > n - 1) lastrow = n - 1;
    int g0 = batch[rowbase0];
    int g1 = batch[lastrow];
    for (int g = g0; g <= g1; g++) {
        float pv[8];
        #pragma unroll
        for (int ct = 0; ct < 8; ct++) pv[ct] = 0.f;
        #pragma unroll
        for (int r = 0; r < 4; r++) {
            if (mygid[r] == g) {
                #pragma unroll
                for (int ct = 0; ct < 8; ct++) pv[ct] += acc2[ct][r];
            }
        }
        #pragma unroll
        for (int ct = 0; ct < 8; ct++) ps[w * 4 + q][ct * 16 + m] = pv[ct];
        __syncthreads();
        if (t < 128) {
            float s = 0.f;
            #pragma unroll
            for (int k = 0; k < 16; k++) s += ps[k][t];
            atomicAdd(&poolc[g * 256 + t], s);
        }
        __syncthreads();
    }
}

// ---------------- head: out[g] = relu(z @ Wl1 + bl1) @ Wl2 + bl2, z = pool[g] ----------------
__global__ void k_head(const float* __restrict__ pool, const float* __restrict__ Wl1,
                       const float* __restrict__ bl1, const float* __restrict__ Wl2,
                       const float* __restrict__ bl2, float* __restrict__ out) {
    int g = blockIdx.x;
    int t = threadIdx.x;
    __shared__ float zmid[64];
    const float* z = pool + g * 256;
    float acc = bl1[t];
    #pragma unroll 8
    for (int k = 0; k < 256; k++) acc = fmaf(z[k], Wl1[k * 64 + t], acc);
    zmid[t] = fmaxf(acc, 0.f);
    __syncthreads();
    if (t < NCLASS) {
        float a = bl2[t];
        #pragma unroll
        for (int j = 0; j < 64; j++) a = fmaf(zmid[j], Wl2[j * 10 + t], a);
        out[g * NCLASS + t] = a;
    }
}

// ---------------- launch ----------------

extern "C" void kernel_launch(void* const* d_in, const int* in_sizes, int n_in,
                              void* d_out, int out_size, void* d_ws, size_t ws_size,
                              hipStream_t stream) {
    const float* x   = (const float*)d_in[0];
    const int* eidx  = (const int*)d_in[1];
    const int* batch = (const int*)d_in[2];
    const float* W1a = (const float*)d_in[3];
    const float* b1a = (const float*)d_in[4];
    const float* g1  = (const float*)d_in[5];
    const float* be1 = (const float*)d_in[6];
    const float* m1  = (const float*)d_in[7];
    const float* v1  = (const float*)d_in[8];
    const float* W1b = (const float*)d_in[9];
    const float* b1b = (const float*)d_in[10];
    const float* W2a = (const float*)d_in[11];
    const float* b2a = (const float*)d_in[12];
    const float* g2  = (const float*)d_in[13];
    const float* be2 = (const float*)d_in[14];
    const float* m2  = (const float*)d_in[15];
    const float* v2  = (const float*)d_in[16];
    const float* W2b = (const float*)d_in[17];
    const float* b2b = (const float*)d_in[18];
    const float* Wl1 = (const float*)d_in[19];
    const float* bl1 = (const float*)d_in[20];
    const float* Wl2 = (const float*)d_in[21];
    const float* bl2 = (const float*)d_in[22];
    const int* srcv = eidx;            // edge_index row 0
    const int* dstv = eidx + N_EDGES;  // edge_index row 1

    char* ws = (char*)d_ws;
    size_t off = 0;
    auto alloc = [&](size_t bytes) -> void* {
        void* p = ws + off;
        off = (off + bytes + 255) & ~(size_t)255;
        return p;
    };
    int* cnt      = (int*)alloc(sizeof(int) * N_NODES);
    unsigned short* adj = (unsigned short*)alloc(sizeof(unsigned short) * (size_t)N_NODES * KSTRIDE);
    float* ep     = (float*)alloc(sizeof(float) * 768);
    float* pool   = (float*)alloc(sizeof(float) * NGRAPH * 256);   // [g][0:128]=p1, [128:256]=p2
    unsigned short* wpack = (unsigned short*)alloc(sizeof(unsigned short) * 4 * 16384);
    unsigned short* xb    = (unsigned short*)alloc(sizeof(unsigned short) * (size_t)N_NODES * HDIM);
    unsigned short* bufA  = (unsigned short*)alloc(sizeof(unsigned short) * (size_t)N_NODES * HDIM);
    unsigned short* bufC  = (unsigned short*)alloc(sizeof(unsigned short) * (size_t)N_NODES * HDIM);
    (void)ws_size; (void)in_sizes; (void)n_in; (void)out_size;

    float* outp = (float*)d_out;

    // zero cnt first (scatter inside k_setup depends on it)
    k_zero<<<dim3((N_NODES + 255) / 256), dim3(256), 0, stream>>>(cnt);
    // setup mega-kernel: interleaved scatter | cast | prepW | poolz | ep
    k_setup<<<dim3(NB_SETUP), dim3(256), 0, stream>>>(
        x, xb, srcv, dstv, cnt, adj, pool, W1a, W1b, W2a, W2b, wpack,
        b1a, g1, be1, m1, v1, b1b, b2a, g2, be2, m2, v2, b2b, ep);

    dim3 agrid((N_NODES * 16 + 255) / 256), ablk(256);
    dim3 mgrid((N_NODES + 63) / 64), mblk(256);

    // conv1: agg(xb) -> bufA; MLP(+pool p1) -> h1 (bufC)
    k_agg<<<agrid, ablk, 0, stream>>>(xb, cnt, adj, bufA);
    k_mlp<<<mgrid, mblk, 0, stream>>>(bufA, wpack + 0 * 16384, wpack + 1 * 16384,
                                      ep + 0, ep + 512, batch, pool + 0, bufC, N_NODES);
    // conv2: agg(h1) -> bufA; MLP(+pool p2), no h2 store
    k_agg<<<agrid, ablk, 0, stream>>>(bufC, cnt, adj, bufA);
    k_mlp<<<mgrid, mblk, 0, stream>>>(bufA, wpack + 2 * 16384, wpack + 3 * 16384,
                                      ep + 256, ep + 640, batch, pool + 128, nullptr, N_NODES);
    // head
    k_head<<<dim3(NGRAPH), dim3(64), 0, stream>>>(pool, Wl1, bl1, Wl2, bl2, outp);
}